// Round 12
// baseline (829.989 us; speedup 1.0000x reference)
//
#include <hip/hip_runtime.h>
#include <math.h>

// Problem constants
#define DMODEL 96
#define DIN    192
#define NST    16
#define RK     6
#define KDIR   4
#define LLEN   4096   // H*W
#define BB     2
#define BP_TOT 8192   // B*L
#define SCH    128    // scan chunks per (b,k)
#define TCH    32     // steps per chunk (L/SCH)

typedef float v2f __attribute__((ext_vector_type(2)));

#if __has_builtin(__builtin_elementwise_fma)
__device__ __forceinline__ v2f pk_fma(v2f a, v2f b, v2f c) { return __builtin_elementwise_fma(a, b, c); }
#else
__device__ __forceinline__ v2f pk_fma(v2f a, v2f b, v2f c) { return a * b + c; }
#endif

// ---------------------------------------------------------------------------
// K1: in_proj. 1024 blocks x 192 thr, 8 positions/block.
__global__ __launch_bounds__(192) void k_inproj(const float* __restrict__ x,
                                                const float* __restrict__ Wp,
                                                float* __restrict__ xi,
                                                float* __restrict__ z)
{
    __shared__ float xs[8 * 96];
    const int t  = threadIdx.x;
    const int p0 = blockIdx.x * 8;
    for (int idx = t; idx < 768; idx += 192)
        xs[idx] = x[(size_t)p0 * 96 + idx];
    __syncthreads();

    float acc0[8], acc1[8];
    #pragma unroll
    for (int i = 0; i < 8; ++i) { acc0[i] = 0.f; acc1[i] = 0.f; }
    const float* w0p = Wp + (size_t)t * 96;
    const float* w1p = Wp + (size_t)(t + 192) * 96;
    for (int k = 0; k < 96; k += 4) {
        float4 w0 = *(const float4*)(w0p + k);
        float4 w1 = *(const float4*)(w1p + k);
        #pragma unroll
        for (int p = 0; p < 8; ++p) {
            float4 xv = *(const float4*)&xs[p * 96 + k];
            acc0[p] = fmaf(w0.x, xv.x, fmaf(w0.y, xv.y, fmaf(w0.z, xv.z, fmaf(w0.w, xv.w, acc0[p]))));
            acc1[p] = fmaf(w1.x, xv.x, fmaf(w1.y, xv.y, fmaf(w1.z, xv.z, fmaf(w1.w, xv.w, acc1[p]))));
        }
    }
    #pragma unroll
    for (int p = 0; p < 8; ++p) {
        xi[(size_t)(p0 + p) * 192 + t] = acc0[p];
        z [(size_t)(p0 + p) * 192 + t] = acc1[p];
    }
}

// ---------------------------------------------------------------------------
__device__ __forceinline__ int inv_perm(int kd, int p)
{
    if (kd == 0) return p;
    if (kd == 1) return ((p & 63) << 6) | (p >> 6);
    if (kd == 2) return 4095 - p;
    return 4095 - (((p & 63) << 6) | (p >> 6));
}

__device__ __forceinline__ int perm_pos(int k, int l)
{
    if (k == 0) return l;
    if (k == 1) return ((l & 63) << 6) | (l >> 6);
    if (k == 2) return 4095 - l;
    int lr = 4095 - l;
    return ((lr & 63) << 6) | (lr >> 6);
}

// within a 32-aligned chunk, perm_pos(k, l0+st) = perm_pos(k,l0) + st*dir
__device__ __forceinline__ int perm_dir(int k)
{
    return (k == 0) ? 1 : (k == 1) ? 64 : (k == 2) ? -1 : -64;
}

__device__ __forceinline__ float softplus_fast(float x)
{
    float r = __logf(1.f + __expf(x));
    return (x > 15.f) ? x : r;
}

// scalar power chain: aa[n] = e1^(n+1)
__device__ __forceinline__ void pow_chain(float e1, float* aa)
{
    float e2 = e1 * e1, e4 = e2 * e2, e8 = e4 * e4, e16 = e8 * e8;
    float e3 = e2 * e1, e5 = e4 * e1, e6 = e4 * e2, e7 = e4 * e3;
    aa[0] = e1;  aa[1] = e2;  aa[2] = e3;  aa[3] = e4;
    aa[4] = e5;  aa[5] = e6;  aa[6] = e7;  aa[7] = e8;
    aa[8] = e8 * e1;  aa[9] = e8 * e2;  aa[10] = e8 * e3;  aa[11] = e8 * e4;
    aa[12] = e8 * e5; aa[13] = e8 * e6; aa[14] = e8 * e7;  aa[15] = e16;
}

// packed power chain: aa[i] = (e1^(2i+1), e1^(2i+2)), i in [0,8)
__device__ __forceinline__ void pow_chain_pk(float e1, v2f* aa)
{
    float e2 = e1 * e1;
    v2f a0; a0.x = e1; a0.y = e2;
    v2f s2; s2.x = e2; s2.y = e2;
    v2f a1 = a0 * s2;                  // e3,e4
    float e4 = a1.y;
    v2f s4; s4.x = e4; s4.y = e4;
    v2f a2 = a0 * s4;                  // e5,e6
    v2f a3 = a1 * s4;                  // e7,e8
    float e8 = a3.y;
    v2f s8; s8.x = e8; s8.y = e8;
    aa[0] = a0; aa[1] = a1; aa[2] = a2; aa[3] = a3;
    aa[4] = a0 * s8;                   // e9,e10
    aa[5] = a1 * s8;                   // e11,e12
    aa[6] = a2 * s8;                   // e13,e14
    aa[7] = a3 * s8;                   // e15,e16
}

// scan-kernel LDS layout per step (stride 40): B[0..15], C[16..31], dt[32..37]
__device__ __forceinline__ int sm_remap(int c)  // src col c: 0..5 dt, 6..21 B, 22..37 C
{
    return (c < 6) ? (32 + c) : (c - 6);
}

// ---------------------------------------------------------------------------
// K2: fused depthwise conv(3x3)+SiLU + x_proj GEMM (scan-ordered out).
// Also zeroes the megascan flags (one per block; grid sizes match).
__global__ __launch_bounds__(192) void k_convxdbl(const float* __restrict__ xi,
                                                  const float* __restrict__ cw,
                                                  const float* __restrict__ cb,
                                                  const float* __restrict__ xpw,
                                                  float* __restrict__ xc,
                                                  float* __restrict__ xdk,
                                                  int* __restrict__ flags)
{
    __shared__ float xs[8 * 192];
    const int t   = threadIdx.x;
    const int p0  = blockIdx.x * 8;
    const int b   = p0 >> 12;
    const int pp0 = p0 & 4095;
    const int row = pp0 >> 6, c0 = pp0 & 63;

    if (t == 0) flags[blockIdx.x] = 0;

    float w9[9];
    #pragma unroll
    for (int i = 0; i < 9; ++i) w9[i] = cw[t * 9 + i];
    const float cbias = cb[t];

    float xv[3][10];
    #pragma unroll
    for (int ky = 0; ky < 3; ++ky) {
        int rr = row + ky - 1;
        #pragma unroll
        for (int kx = 0; kx < 10; ++kx) {
            int cc = c0 + kx - 1;
            float v = 0.f;
            if (rr >= 0 && rr < 64 && cc >= 0 && cc < 64)
                v = xi[((size_t)b * 4096 + rr * 64 + cc) * 192 + t];
            xv[ky][kx] = v;
        }
    }
    #pragma unroll
    for (int p = 0; p < 8; ++p) {
        float s = cbias;
        #pragma unroll
        for (int ky = 0; ky < 3; ++ky)
            #pragma unroll
            for (int kx = 0; kx < 3; ++kx)
                s = fmaf(xv[ky][p + kx], w9[ky * 3 + kx], s);
        float sv = s * (1.f / (1.f + __expf(-s)));   // SiLU
        xc[(size_t)(p0 + p) * 192 + t] = sv;
        xs[p * 192 + t] = sv;
    }
    __syncthreads();
    if (t >= 152) return;

    const int kd = t / 38, r = t % 38;
    float acc[8];
    #pragma unroll
    for (int i = 0; i < 8; ++i) acc[i] = 0.f;
    const float* wr = xpw + (size_t)t * 192;
    for (int k = 0; k < 192; k += 4) {
        float4 w = *(const float4*)(wr + k);
        #pragma unroll
        for (int p = 0; p < 8; ++p) {
            float4 x4 = *(const float4*)&xs[p * 192 + k];
            acc[p] = fmaf(w.x, x4.x, fmaf(w.y, x4.y, fmaf(w.z, x4.z, fmaf(w.w, x4.w, acc[p]))));
        }
    }
    #pragma unroll
    for (int p = 0; p < 8; ++p) {
        int pp = pp0 + p;
        int l  = inv_perm(kd, pp);
        xdk[((size_t)(b * 4 + kd) * 4096 + l) * 38 + r] = acc[p];
    }
}

// ---------------------------------------------------------------------------
// K3: single-pass scan with decoupled look-back.
// Phase 1: local recurrence from h=0, y_loc (C·h_loc + D·u) stashed into su.
// Publish (h_agg, W) flag=1 (s==0: inclusive, flag=2). Look-back to get
// h_init. Publish inclusive. Phase 2: y = y_loc + C·(W_prefix^(n+1)·h_init).
// Co-residency: 1024 blocks, 29.7 KB LDS -> 5 blocks/CU >= 4 needed, so all
// blocks resident -> spin-wait is deadlock-free.
__global__ __launch_bounds__(192) void k_megascan(const float* __restrict__ xc,
                                                  const float* __restrict__ xdk,
                                                  const float* __restrict__ dtw,
                                                  const float* __restrict__ dtb,
                                                  const float* __restrict__ Alog,
                                                  const float* __restrict__ Ds,
                                                  float* __restrict__ hagg,
                                                  float* __restrict__ hinc,
                                                  float* __restrict__ Wagg,
                                                  float* __restrict__ prodA,
                                                  int* __restrict__ flags,
                                                  float* __restrict__ yk)
{
    __shared__ float sm[TCH * 40];
    __shared__ float su[TCH * 192];
    const int t   = threadIdx.x;
    const int blk = blockIdx.x;
    const int s = blk & (SCH - 1), k = (blk >> 7) & 3, b = blk >> 9;
    const int kd = k * 192 + t;
    const int l0 = s * TCH;
    const int pstart = perm_pos(k, l0);
    const int dir    = perm_dir(k);

    const float* src = xdk + ((size_t)(b * 4 + k) * 4096 + l0) * 38;
    for (int idx = t; idx < TCH * 38; idx += 192) {
        int st = idx / 38, c = idx % 38;
        sm[st * 40 + sm_remap(c)] = src[idx];
    }
    const float* xcb = xc + (size_t)b * 4096 * 192;
    #pragma unroll
    for (int i = 0; i < TCH; ++i)
        su[i * 192 + t] = xcb[(size_t)(pstart + i * dir) * 192 + t];

    const float A0 = -__expf(Alog[kd * 16]);
    bool fast = true;
    #pragma unroll
    for (int n = 1; n < 16; ++n) {
        float An = -__expf(Alog[kd * 16 + n]);
        fast = fast && (fabsf(An - (float)(n + 1) * A0) <= 1e-3f * fabsf(An));
    }
    float wdt[6];
    #pragma unroll
    for (int r = 0; r < 6; ++r) wdt[r] = dtw[kd * 6 + r];
    const float bias = dtb[kd];
    const float Dk   = Ds[kd];

    __syncthreads();

    const size_t base = (size_t)blk * 3072 + t * 16;
    float he[16];          // local h_end
    float Wl = 1.f;        // product of e1 over chunk (fast path)
    float cd = 0.f;        // sum of deltas (slow path)

    // ---------------- phase 1: local recurrence, y_loc into su -------------
    if (fast) {
        v2f h2[8];
        #pragma unroll
        for (int i = 0; i < 8; ++i) { h2[i].x = 0.f; h2[i].y = 0.f; }
        for (int st = 0; st < TCH; ++st) {
            const float* r = &sm[st * 40];
            float u = su[st * 192 + t];
            float4 dq = *(const float4*)(r + 32);
            float xv = bias + dq.x * wdt[0] + dq.y * wdt[1] + dq.z * wdt[2]
                            + dq.w * wdt[3] + r[36] * wdt[4] + r[37] * wdt[5];
            float delta = softplus_fast(xv);
            float e1 = __expf(delta * A0);
            Wl *= e1;
            float du = delta * u;
            v2f du2; du2.x = du; du2.y = du;
            v2f aa2[8];
            pow_chain_pk(e1, aa2);
            const v2f* rb = (const v2f*)r;
            const v2f* rc = (const v2f*)(r + 16);
            v2f acc2; acc2.x = Dk * u; acc2.y = 0.f;
            #pragma unroll
            for (int i = 0; i < 8; ++i) {
                h2[i] = pk_fma(h2[i], aa2[i], du2 * rb[i]);
                acc2  = pk_fma(h2[i], rc[i], acc2);
            }
            su[st * 192 + t] = acc2.x + acc2.y;   // stash y_loc (own slot)
        }
        #pragma unroll
        for (int i = 0; i < 8; ++i) { he[2*i] = h2[i].x; he[2*i+1] = h2[i].y; }
        Wagg[(size_t)blk * 192 + t] = Wl;
    } else {
        #pragma unroll
        for (int n = 0; n < 16; ++n) he[n] = 0.f;
        for (int st = 0; st < TCH; ++st) {
            const float* r = &sm[st * 40];
            float u = su[st * 192 + t];           // u left intact for phase 2
            float xv = bias;
            #pragma unroll
            for (int j = 0; j < 6; ++j) xv += r[32 + j] * wdt[j];
            float delta = softplus_fast(xv);
            cd += delta;
            float du = delta * u;
            #pragma unroll
            for (int n = 0; n < 16; ++n) {
                float An = -__expf(Alog[kd * 16 + n]);
                he[n] = fmaf(he[n], __expf(delta * An), du * r[n]);
            }
        }
        #pragma unroll
        for (int n = 0; n < 16; ++n)
            prodA[base + n] = __expf(-__expf(Alog[kd * 16 + n]) * cd);
    }
    #pragma unroll
    for (int i = 0; i < 4; ++i)
        *(float4*)&hagg[base + 4 * i] = make_float4(he[4*i], he[4*i+1], he[4*i+2], he[4*i+3]);

    // ---------------- publish ----------------------------------------------
    if (s == 0) {
        #pragma unroll
        for (int i = 0; i < 4; ++i)
            *(float4*)&hinc[base + 4 * i] = make_float4(he[4*i], he[4*i+1], he[4*i+2], he[4*i+3]);
        __threadfence();
        __syncthreads();
        if (t == 0) __hip_atomic_store(&flags[blk], 2, __ATOMIC_RELEASE, __HIP_MEMORY_SCOPE_AGENT);
    } else {
        __threadfence();
        __syncthreads();
        if (t == 0) __hip_atomic_store(&flags[blk], 1, __ATOMIC_RELEASE, __HIP_MEMORY_SCOPE_AGENT);
    }

    float H[16];
    #pragma unroll
    for (int n = 0; n < 16; ++n) H[n] = 0.f;

    if (s > 0) {
        // ---------------- look-back ----------------------------------------
        if (fast) {
            float Pw = 1.f;
            int j = blk - 1;
            while (true) {
                int f;
                do { f = __hip_atomic_load(&flags[j], __ATOMIC_ACQUIRE, __HIP_MEMORY_SCOPE_AGENT); } while (f == 0);
                float aaP[16];
                pow_chain(Pw, aaP);
                const float* hj = ((f == 2) ? hinc : hagg) + (size_t)j * 3072 + t * 16;
                #pragma unroll
                for (int n = 0; n < 16; ++n) H[n] = fmaf(aaP[n], hj[n], H[n]);
                if (f == 2) break;
                Pw *= Wagg[(size_t)j * 192 + t];
                --j;
            }
        } else {
            float P[16];
            #pragma unroll
            for (int n = 0; n < 16; ++n) P[n] = 1.f;
            int j = blk - 1;
            while (true) {
                int f;
                do { f = __hip_atomic_load(&flags[j], __ATOMIC_ACQUIRE, __HIP_MEMORY_SCOPE_AGENT); } while (f == 0);
                const float* hj = ((f == 2) ? hinc : hagg) + (size_t)j * 3072 + t * 16;
                #pragma unroll
                for (int n = 0; n < 16; ++n) H[n] = fmaf(P[n], hj[n], H[n]);
                if (f == 2) break;
                const float* aj = prodA + (size_t)j * 3072 + t * 16;
                #pragma unroll
                for (int n = 0; n < 16; ++n) P[n] *= aj[n];
                --j;
            }
        }
        // publish inclusive: h_inc = a_local∘h_init + h_end
        float aaL[16];
        if (fast) {
            pow_chain(Wl, aaL);
        } else {
            #pragma unroll
            for (int n = 0; n < 16; ++n) aaL[n] = prodA[base + n];
        }
        #pragma unroll
        for (int i = 0; i < 4; ++i) {
            float4 v;
            v.x = fmaf(aaL[4*i],   H[4*i],   he[4*i]);
            v.y = fmaf(aaL[4*i+1], H[4*i+1], he[4*i+1]);
            v.z = fmaf(aaL[4*i+2], H[4*i+2], he[4*i+2]);
            v.w = fmaf(aaL[4*i+3], H[4*i+3], he[4*i+3]);
            *(float4*)&hinc[base + 4 * i] = v;
        }
        __threadfence();
        __syncthreads();
        if (t == 0) __hip_atomic_store(&flags[blk], 2, __ATOMIC_RELEASE, __HIP_MEMORY_SCOPE_AGENT);
    }

    // ---------------- phase 2: correction + final y write ------------------
    float* yp = yk + (size_t)(b * 4 + k) * 4096 * 192 + (size_t)pstart * 192 + t;
    const int ystep = dir * 192;

    if (fast) {
        if (s == 0) {
            #pragma unroll
            for (int st = 0; st < TCH; ++st) {
                *yp = su[st * 192 + t];
                yp += ystep;
            }
        } else {
            v2f Hq[8];
            #pragma unroll
            for (int i = 0; i < 8; ++i) { Hq[i].x = H[2*i]; Hq[i].y = H[2*i+1]; }
            float Wr = 1.f;
            for (int st = 0; st < TCH; ++st) {
                const float* r = &sm[st * 40];
                float4 dq = *(const float4*)(r + 32);
                float xv = bias + dq.x * wdt[0] + dq.y * wdt[1] + dq.z * wdt[2]
                                + dq.w * wdt[3] + r[36] * wdt[4] + r[37] * wdt[5];
                float delta = softplus_fast(xv);
                Wr *= __expf(delta * A0);
                v2f aaW[8];
                pow_chain_pk(Wr, aaW);
                const v2f* rc = (const v2f*)(r + 16);
                v2f corr2; corr2.x = 0.f; corr2.y = 0.f;
                #pragma unroll
                for (int i = 0; i < 8; ++i)
                    corr2 = pk_fma(aaW[i] * Hq[i], rc[i], corr2);
                *yp = su[st * 192 + t] + corr2.x + corr2.y;
                yp += ystep;
            }
        }
    } else {
        float h[16];
        #pragma unroll
        for (int n = 0; n < 16; ++n) h[n] = H[n];
        for (int st = 0; st < TCH; ++st) {
            const float* r = &sm[st * 40];
            float u = su[st * 192 + t];           // still u (never stashed)
            float xv = bias;
            #pragma unroll
            for (int j = 0; j < 6; ++j) xv += r[32 + j] * wdt[j];
            float delta = softplus_fast(xv);
            float du = delta * u;
            float acc = Dk * u;
            #pragma unroll
            for (int n = 0; n < 16; ++n) {
                float An = -__expf(Alog[kd * 16 + n]);
                h[n] = fmaf(h[n], __expf(delta * An), du * r[n]);
                acc  = fmaf(h[n], r[16 + n], acc);
            }
            *yp = acc;
            yp += ystep;
        }
    }
}

// ---------------------------------------------------------------------------
// K4: sum 4 direction buffers + LayerNorm + SiLU gate + out_proj.
__global__ __launch_bounds__(192) void k_lnout(const float* __restrict__ yk,
                                               const float* __restrict__ zb,
                                               const float* __restrict__ onw,
                                               const float* __restrict__ onb,
                                               const float* __restrict__ Wo,
                                               float* __restrict__ out)
{
    __shared__ float ys[1536];
    __shared__ float ps[192], pq[192];
    __shared__ float mu[8], ri[8];
    const int t   = threadIdx.x;
    const int p0  = blockIdx.x * 8;
    const int b   = p0 >> 12;
    const int pp0 = p0 & 4095;
    const size_t KSTR = (size_t)4096 * 192;

    #pragma unroll
    for (int i = 0; i < 8; ++i) {
        size_t base = ((size_t)(b * 4) * 4096 + pp0 + i) * 192 + t;
        ys[i * 192 + t] = yk[base] + yk[base + KSTR] + yk[base + 2 * KSTR] + yk[base + 3 * KSTR];
    }
    __syncthreads();

    {
        int pg = t / 24, j = t % 24;
        float s1 = 0.f, s2 = 0.f;
        #pragma unroll
        for (int m = 0; m < 8; ++m) {
            float v = ys[pg * 192 + j + 24 * m];
            s1 += v; s2 += v * v;
        }
        ps[t] = s1; pq[t] = s2;
    }
    __syncthreads();
    if (t < 8) {
        float s1 = 0.f, s2 = 0.f;
        #pragma unroll
        for (int j = 0; j < 24; ++j) { s1 += ps[t * 24 + j]; s2 += pq[t * 24 + j]; }
        float mean = s1 * (1.f / 192.f);
        float var  = s2 * (1.f / 192.f) - mean * mean;
        mu[t] = mean;
        ri[t] = rsqrtf(var + 1e-5f);
    }
    __syncthreads();

    {
        float w = onw[t], bo = onb[t];
        #pragma unroll
        for (int i = 0; i < 8; ++i) {
            float v  = ys[i * 192 + t];
            float yn = (v - mu[i]) * ri[i] * w + bo;
            float zv = zb[(size_t)(p0 + i) * 192 + t];
            float sg = 1.f / (1.f + __expf(-zv));
            ys[i * 192 + t] = yn * (zv * sg);
        }
    }
    __syncthreads();

    const int pg = t / 96, c = t % 96;
    float acc[4];
    #pragma unroll
    for (int i = 0; i < 4; ++i) acc[i] = 0.f;
    const float* wr = Wo + (size_t)c * 192;
    for (int k = 0; k < 192; k += 4) {
        float4 w = *(const float4*)(wr + k);
        #pragma unroll
        for (int i = 0; i < 4; ++i) {
            float4 xv = *(const float4*)&ys[(pg * 4 + i) * 192 + k];
            acc[i] = fmaf(w.x, xv.x, fmaf(w.y, xv.y, fmaf(w.z, xv.z, fmaf(w.w, xv.w, acc[i]))));
        }
    }
    #pragma unroll
    for (int i = 0; i < 4; ++i)
        out[(size_t)(p0 + pg * 4 + i) * 96 + c] = acc[i];
}

// ---------------------------------------------------------------------------
extern "C" void kernel_launch(void* const* d_in, const int* in_sizes, int n_in,
                              void* d_out, int out_size, void* d_ws, size_t ws_size,
                              hipStream_t stream)
{
    const float* x    = (const float*)d_in[0];
    const float* Wp   = (const float*)d_in[1];
    const float* cw   = (const float*)d_in[2];
    const float* cb   = (const float*)d_in[3];
    const float* xpw  = (const float*)d_in[4];
    const float* dtw  = (const float*)d_in[5];
    const float* dtb  = (const float*)d_in[6];
    const float* Alog = (const float*)d_in[7];
    const float* Ds   = (const float*)d_in[8];
    const float* onw  = (const float*)d_in[9];
    const float* onb  = (const float*)d_in[10];
    const float* Wo   = (const float*)d_in[11];
    float* out = (float*)d_out;

    const size_t NBP  = (size_t)BP_TOT * 192;        // 1.57M floats
    const size_t NXD  = (size_t)BB * 4 * 4096 * 38;  // 1.25M floats
    const size_t NSC  = (size_t)BB * 4 * SCH * 3072; // 3.15M floats
    const size_t NW   = (size_t)BB * 4 * SCH * 192;  // 0.20M floats
    float* WS    = (float*)d_ws;
    float* xibuf = WS;                  // in_proj x-branch (conv input)
    float* zb    = WS + NBP;            // gate z
    float* xc    = WS + 2 * NBP;        // conv output (scan u)
    float* xdk   = WS + 3 * NBP;        // (b,k,l,38) scan-ordered x_dbl
    float* hagg  = xdk + NXD;           // per-chunk aggregate h_end
    float* hinc  = hagg + NSC;          // per-chunk inclusive prefix h
    float* prodA = hinc + NSC;          // slow-path per-chunk a[16]
    float* Wagg  = prodA + NSC;         // fast-path scalar chunk decay
    int*   flags = (int*)(Wagg + NW);   // look-back flags (1024)
    float* yk    = Wagg + NW + 16384;   // 4 per-direction y buffers (25 MB)

    k_inproj  <<<1024, 192, 0, stream>>>(x, Wp, xibuf, zb);
    k_convxdbl<<<1024, 192, 0, stream>>>(xibuf, cw, cb, xpw, xc, xdk, flags);
    k_megascan<<<1024, 192, 0, stream>>>(xc, xdk, dtw, dtb, Alog, Ds,
                                         hagg, hinc, Wagg, prodA, flags, yk);
    k_lnout   <<<1024, 192, 0, stream>>>(yk, zb, onw, onb, Wo, out);
}

// Round 13
// 226.541 us; speedup vs baseline: 3.6637x; 3.6637x over previous
//
#include <hip/hip_runtime.h>
#include <math.h>

// Problem constants
#define DMODEL 96
#define DIN    192
#define NST    16
#define RK     6
#define KDIR   4
#define LLEN   4096   // H*W
#define BB     2
#define BP_TOT 8192   // B*L
#define SCH    128    // scan chunks per (b,k)
#define TCH    32     // steps per chunk (L/SCH)

typedef float v2f __attribute__((ext_vector_type(2)));

#if __has_builtin(__builtin_elementwise_fma)
__device__ __forceinline__ v2f pk_fma(v2f a, v2f b, v2f c) { return __builtin_elementwise_fma(a, b, c); }
#else
__device__ __forceinline__ v2f pk_fma(v2f a, v2f b, v2f c) { return a * b + c; }
#endif

// ---------------------------------------------------------------------------
__device__ __forceinline__ int inv_perm(int kd, int p)
{
    if (kd == 0) return p;
    if (kd == 1) return ((p & 63) << 6) | (p >> 6);
    if (kd == 2) return 4095 - p;
    return 4095 - (((p & 63) << 6) | (p >> 6));
}

__device__ __forceinline__ int perm_pos(int k, int l)
{
    if (k == 0) return l;
    if (k == 1) return ((l & 63) << 6) | (l >> 6);
    if (k == 2) return 4095 - l;
    int lr = 4095 - l;
    return ((lr & 63) << 6) | (lr >> 6);
}

// within a 32-aligned chunk, perm_pos(k, l0+st) = perm_pos(k,l0) + st*dir
__device__ __forceinline__ int perm_dir(int k)
{
    return (k == 0) ? 1 : (k == 1) ? 64 : (k == 2) ? -1 : -64;
}

__device__ __forceinline__ float softplus_fast(float x)
{
    float r = __logf(1.f + __expf(x));
    return (x > 15.f) ? x : r;
}

// packed power chain: aa[i] = (e1^(2i+1), e1^(2i+2)), i in [0,8)
__device__ __forceinline__ void pow_chain_pk(float e1, v2f* aa)
{
    float e2 = e1 * e1;
    v2f a0; a0.x = e1; a0.y = e2;
    v2f s2; s2.x = e2; s2.y = e2;
    v2f a1 = a0 * s2;                  // e3,e4
    float e4 = a1.y;
    v2f s4; s4.x = e4; s4.y = e4;
    v2f a2 = a0 * s4;                  // e5,e6
    v2f a3 = a1 * s4;                  // e7,e8
    float e8 = a3.y;
    v2f s8; s8.x = e8; s8.y = e8;
    aa[0] = a0; aa[1] = a1; aa[2] = a2; aa[3] = a3;
    aa[4] = a0 * s8;                   // e9,e10
    aa[5] = a1 * s8;                   // e11,e12
    aa[6] = a2 * s8;                   // e13,e14
    aa[7] = a3 * s8;                   // e15,e16
}

// single power W^(n+1), e = n+1 in [1,16]
__device__ __forceinline__ float pow_n(float W, int e)
{
    float w2 = W * W, w4 = w2 * w2, w8 = w4 * w4;
    float r = 1.f;
    if (e & 1) r *= W;
    if (e & 2) r *= w2;
    if (e & 4) r *= w4;
    if (e & 8) r *= w8;
    if (e & 16) r = w8 * w8;
    return r;
}

// scan-kernel LDS layout per step (stride 40): B[0..15], C[16..31], dt[32..37]
__device__ __forceinline__ int sm_remap(int c)  // src col c: 0..5 dt, 6..21 B, 22..37 C
{
    return (c < 6) ? (32 + c) : (c - 6);
}

// ---------------------------------------------------------------------------
// K1: FUSED in_proj + depthwise conv(3x3)+SiLU + x_proj GEMM.
// Block = 8 consecutive row-major positions. Stages the 3x10 x-halo in LDS,
// computes xi = Wp·x for all 30 halo positions in registers (redundant but
// cheap), conv+SiLU in registers, z in the same pass, then the x_proj GEMM
// from the LDS tile. Eliminates the xi round-trip and one dispatch.
__global__ __launch_bounds__(192) void k_fused(const float* __restrict__ x,
                                               const float* __restrict__ Wp,
                                               const float* __restrict__ cw,
                                               const float* __restrict__ cb,
                                               const float* __restrict__ xpw,
                                               float* __restrict__ z,
                                               float* __restrict__ xc,
                                               float* __restrict__ xdk)
{
    __shared__ float xh[30 * 96];   // 3x10 halo positions x 96 channels
    __shared__ float xs[8 * 192];   // conv output tile for x_proj GEMM
    const int t   = threadIdx.x;
    const int p0  = blockIdx.x * 8;
    const int b   = p0 >> 12;
    const int pp0 = p0 & 4095;
    const int row = pp0 >> 6, c0 = pp0 & 63;

    for (int idx = t; idx < 2880; idx += 192) {
        int hp = idx / 96, kk = idx - hp * 96;
        int rr = row + hp / 10 - 1;
        int cc = c0 + hp % 10 - 1;
        float v = 0.f;
        if (rr >= 0 && rr < 64 && cc >= 0 && cc < 64)
            v = x[((size_t)b * 4096 + rr * 64 + cc) * 96 + kk];
        xh[idx] = v;
    }
    __syncthreads();

    // xi for 30 halo positions (this thread's channel t) + z for own 8
    float acc[30], accz[8];
    #pragma unroll
    for (int i = 0; i < 30; ++i) acc[i] = 0.f;
    #pragma unroll
    for (int i = 0; i < 8; ++i) accz[i] = 0.f;
    const float* w0p = Wp + (size_t)t * 96;
    const float* w1p = Wp + (size_t)(t + 192) * 96;
    for (int k = 0; k < 96; k += 4) {
        float4 w0 = *(const float4*)(w0p + k);
        float4 w1 = *(const float4*)(w1p + k);
        #pragma unroll
        for (int hp = 0; hp < 30; ++hp) {
            float4 xv = *(const float4*)&xh[hp * 96 + k];
            acc[hp] = fmaf(w0.x, xv.x, fmaf(w0.y, xv.y, fmaf(w0.z, xv.z, fmaf(w0.w, xv.w, acc[hp]))));
        }
        #pragma unroll
        for (int p = 0; p < 8; ++p) {
            float4 xv = *(const float4*)&xh[(11 + p) * 96 + k];
            accz[p] = fmaf(w1.x, xv.x, fmaf(w1.y, xv.y, fmaf(w1.z, xv.z, fmaf(w1.w, xv.w, accz[p]))));
        }
    }

    // depthwise 3x3 conv + SiLU, entirely in registers
    float w9[9];
    #pragma unroll
    for (int i = 0; i < 9; ++i) w9[i] = cw[t * 9 + i];
    const float cbias = cb[t];
    #pragma unroll
    for (int p = 0; p < 8; ++p) {
        float s = cbias;
        #pragma unroll
        for (int ky = 0; ky < 3; ++ky)
            #pragma unroll
            for (int kx = 0; kx < 3; ++kx)
                s = fmaf(acc[ky * 10 + p + kx], w9[ky * 3 + kx], s);
        float sv = s * (1.f / (1.f + __expf(-s)));   // SiLU
        xc[(size_t)(p0 + p) * 192 + t] = sv;
        xs[p * 192 + t] = sv;
        z[(size_t)(p0 + p) * 192 + t] = accz[p];
    }
    __syncthreads();
    if (t >= 152) return;

    // x_proj GEMM (scan-ordered out)
    const int kd = t / 38, r = t % 38;
    float pacc[8];
    #pragma unroll
    for (int i = 0; i < 8; ++i) pacc[i] = 0.f;
    const float* wr = xpw + (size_t)t * 192;
    for (int k = 0; k < 192; k += 4) {
        float4 w = *(const float4*)(wr + k);
        #pragma unroll
        for (int p = 0; p < 8; ++p) {
            float4 x4 = *(const float4*)&xs[p * 192 + k];
            pacc[p] = fmaf(w.x, x4.x, fmaf(w.y, x4.y, fmaf(w.z, x4.z, fmaf(w.w, x4.w, pacc[p]))));
        }
    }
    #pragma unroll
    for (int p = 0; p < 8; ++p) {
        int pp = pp0 + p;
        int l  = inv_perm(kd, pp);
        xdk[((size_t)(b * 4 + kd) * 4096 + l) * 38 + r] = pacc[p];
    }
}

// ---------------------------------------------------------------------------
// K2: scan pass 1 — local recurrence from h=0. Pure LDS+VALU inner loop;
// fast path packed fp32. Stores h_end and W (fast) / prodA (general).
__global__ __launch_bounds__(192) void k_scan1(const float* __restrict__ xc,
                                               const float* __restrict__ xdk,
                                               const float* __restrict__ dtw,
                                               const float* __restrict__ dtb,
                                               const float* __restrict__ Alog,
                                               float* __restrict__ hend,
                                               float* __restrict__ prodA,
                                               float* __restrict__ Wbuf)
{
    __shared__ float sm[TCH * 40];
    __shared__ float su[TCH * 192];
    const int t   = threadIdx.x;
    const int blk = blockIdx.x;
    const int s = blk & (SCH - 1), k = (blk >> 7) & 3, b = blk >> 9;
    const int kd = k * 192 + t;
    const int l0 = s * TCH;
    const int pstart = perm_pos(k, l0);
    const int dir    = perm_dir(k);

    const float* src = xdk + ((size_t)(b * 4 + k) * 4096 + l0) * 38;
    for (int idx = t; idx < TCH * 38; idx += 192) {
        int st = idx / 38, c = idx % 38;
        sm[st * 40 + sm_remap(c)] = src[idx];
    }
    const float* xcb = xc + (size_t)b * 4096 * 192;
    #pragma unroll
    for (int i = 0; i < TCH; ++i)
        su[i * 192 + t] = xcb[(size_t)(pstart + i * dir) * 192 + t];

    const float A0 = -__expf(Alog[kd * 16]);
    bool fast = true;
    #pragma unroll
    for (int n = 1; n < 16; ++n) {
        float An = -__expf(Alog[kd * 16 + n]);
        fast = fast && (fabsf(An - (float)(n + 1) * A0) <= 1e-3f * fabsf(An));
    }
    float wdt[6];
    #pragma unroll
    for (int r = 0; r < 6; ++r) wdt[r] = dtw[kd * 6 + r];
    const float bias = dtb[kd];

    __syncthreads();

    size_t base = (size_t)blk * 3072 + t * 16;

    if (fast) {
        v2f h2[8];
        #pragma unroll
        for (int i = 0; i < 8; ++i) { h2[i].x = 0.f; h2[i].y = 0.f; }
        float cd = 0.f;
        for (int st = 0; st < TCH; ++st) {
            const float* r = &sm[st * 40];
            float u = su[st * 192 + t];
            float4 dq = *(const float4*)(r + 32);
            float xv = bias + dq.x * wdt[0] + dq.y * wdt[1] + dq.z * wdt[2]
                            + dq.w * wdt[3] + r[36] * wdt[4] + r[37] * wdt[5];
            float delta = softplus_fast(xv);
            cd += delta;
            float du = delta * u;
            v2f du2; du2.x = du; du2.y = du;
            v2f aa2[8];
            pow_chain_pk(__expf(delta * A0), aa2);
            const v2f* rb = (const v2f*)r;
            #pragma unroll
            for (int i = 0; i < 8; ++i)
                h2[i] = pk_fma(h2[i], aa2[i], du2 * rb[i]);
        }
        Wbuf[(size_t)blk * 192 + t] = __expf(cd * A0);
        #pragma unroll
        for (int i = 0; i < 4; ++i)
            *(float4*)&hend[base + 4 * i] =
                make_float4(h2[2*i].x, h2[2*i].y, h2[2*i+1].x, h2[2*i+1].y);
    } else {
        float h[16];
        #pragma unroll
        for (int n = 0; n < 16; ++n) h[n] = 0.f;
        float cd = 0.f;
        for (int st = 0; st < TCH; ++st) {
            const float* r = &sm[st * 40];
            float u = su[st * 192 + t];
            float xv = bias;
            #pragma unroll
            for (int j = 0; j < 6; ++j) xv += r[32 + j] * wdt[j];
            float delta = softplus_fast(xv);
            cd += delta;
            float du = delta * u;
            #pragma unroll
            for (int n = 0; n < 16; ++n) {
                float An = -__expf(Alog[kd * 16 + n]);
                h[n] = fmaf(h[n], __expf(delta * An), du * r[n]);
            }
        }
        #pragma unroll
        for (int n = 0; n < 16; ++n)
            prodA[base + n] = __expf(-__expf(Alog[kd * 16 + n]) * cd);
        #pragma unroll
        for (int i = 0; i < 4; ++i)
            *(float4*)&hend[base + 4 * i] = make_float4(h[4*i], h[4*i+1], h[4*i+2], h[4*i+3]);
    }
}

// ---------------------------------------------------------------------------
// K3: scan pass 2 — parallel chunk composition. Block=(b,k,d). Fast path
// reconstructs a[n] = W^(n+1) from the scalar Wbuf. Writes h_init into prodA.
__global__ __launch_bounds__(256) void k_scan2(const float* __restrict__ hend,
                                               float* __restrict__ prodA,
                                               const float* __restrict__ Wbuf,
                                               const float* __restrict__ Alog)
{
    __shared__ float smA[256], smH[256];
    const int t = threadIdx.x;
    const int g = t >> 4, n = t & 15;
    const int bk = blockIdx.x / 192, d = blockIdx.x % 192;
    const int kd = (bk & 3) * 192 + d;
    const size_t base = (size_t)bk * SCH * 3072 + d * 16 + n;

    const float A0 = -__expf(Alog[kd * 16]);
    bool fast = true;
    #pragma unroll
    for (int m = 1; m < 16; ++m) {
        float An = -__expf(Alog[kd * 16 + m]);
        fast = fast && (fabsf(An - (float)(m + 1) * A0) <= 1e-3f * fabsf(An));
    }

    float a_[8], h_[8];
    float A = 1.f, H = 0.f;
    #pragma unroll
    for (int i = 0; i < 8; ++i) {
        int s = g * 8 + i;
        size_t rec = base + (size_t)s * 3072;
        float ai;
        if (fast) {
            float W = Wbuf[((size_t)bk * SCH + s) * 192 + d];
            ai = pow_n(W, n + 1);
        } else {
            ai = prodA[rec];
        }
        a_[i] = ai;
        h_[i] = hend[rec];
        H = fmaf(ai, H, h_[i]);
        A *= ai;
    }
    smA[t] = A; smH[t] = H;
    __syncthreads();
    if (t < 16) {
        float carry = 0.f;
        for (int g2 = 0; g2 < 16; ++g2) {
            float ta = smA[g2 * 16 + t], th = smH[g2 * 16 + t];
            smH[g2 * 16 + t] = carry;          // exclusive carry into group g2
            carry = fmaf(ta, carry, th);
        }
    }
    __syncthreads();
    float carry = smH[t];
    #pragma unroll
    for (int i = 0; i < 8; ++i) {
        size_t rec = base + (size_t)(g * 8 + i) * 3072;
        prodA[rec] = carry;                    // h_init
        carry = fmaf(a_[i], carry, h_[i]);
    }
}

// ---------------------------------------------------------------------------
// K4: scan pass 3 — full replay from h_init, write yk once (plain stores).
// Packed fp32 fast path; incremental y pointer.
__global__ __launch_bounds__(192) void k_scan3(const float* __restrict__ xc,
                                               const float* __restrict__ xdk,
                                               const float* __restrict__ dtw,
                                               const float* __restrict__ dtb,
                                               const float* __restrict__ Alog,
                                               const float* __restrict__ Ds,
                                               const float* __restrict__ hinit,
                                               float* __restrict__ yk)
{
    __shared__ float sm[TCH * 40];
    __shared__ float su[TCH * 192];
    const int t   = threadIdx.x;
    const int blk = blockIdx.x;
    const int s = blk & (SCH - 1), k = (blk >> 7) & 3, b = blk >> 9;
    const int kd = k * 192 + t;
    const int l0 = s * TCH;
    const int pstart = perm_pos(k, l0);
    const int dir    = perm_dir(k);

    const float* src = xdk + ((size_t)(b * 4 + k) * 4096 + l0) * 38;
    for (int idx = t; idx < TCH * 38; idx += 192) {
        int st = idx / 38, c = idx % 38;
        sm[st * 40 + sm_remap(c)] = src[idx];
    }
    const float* xcb = xc + (size_t)b * 4096 * 192;
    #pragma unroll
    for (int i = 0; i < TCH; ++i)
        su[i * 192 + t] = xcb[(size_t)(pstart + i * dir) * 192 + t];

    const float A0 = -__expf(Alog[kd * 16]);
    bool fast = true;
    #pragma unroll
    for (int n = 1; n < 16; ++n) {
        float An = -__expf(Alog[kd * 16 + n]);
        fast = fast && (fabsf(An - (float)(n + 1) * A0) <= 1e-3f * fabsf(An));
    }
    float wdt[6];
    #pragma unroll
    for (int r = 0; r < 6; ++r) wdt[r] = dtw[kd * 6 + r];
    const float bias = dtb[kd];
    const float Dk   = Ds[kd];

    size_t hbase = (size_t)blk * 3072 + t * 16;
    float* yp = yk + (size_t)(b * 4 + k) * 4096 * 192 + (size_t)pstart * 192 + t;
    const int ystep = dir * 192;

    __syncthreads();

    if (fast) {
        v2f h2[8];
        #pragma unroll
        for (int i = 0; i < 4; ++i) {
            float4 v = *(const float4*)&hinit[hbase + 4 * i];
            h2[2*i].x = v.x; h2[2*i].y = v.y; h2[2*i+1].x = v.z; h2[2*i+1].y = v.w;
        }
        for (int st = 0; st < TCH; ++st) {
            const float* r = &sm[st * 40];
            float u = su[st * 192 + t];
            float4 dq = *(const float4*)(r + 32);
            float xv = bias + dq.x * wdt[0] + dq.y * wdt[1] + dq.z * wdt[2]
                            + dq.w * wdt[3] + r[36] * wdt[4] + r[37] * wdt[5];
            float delta = softplus_fast(xv);
            float du = delta * u;
            v2f du2; du2.x = du; du2.y = du;
            v2f aa2[8];
            pow_chain_pk(__expf(delta * A0), aa2);
            const v2f* rb = (const v2f*)r;
            const v2f* rc = (const v2f*)(r + 16);
            v2f acc2; acc2.x = Dk * u; acc2.y = 0.f;
            #pragma unroll
            for (int i = 0; i < 8; ++i) {
                h2[i] = pk_fma(h2[i], aa2[i], du2 * rb[i]);
                acc2  = pk_fma(h2[i], rc[i], acc2);
            }
            *yp = acc2.x + acc2.y;             // plain store, owner-exclusive
            yp += ystep;
        }
    } else {
        float h[16];
        #pragma unroll
        for (int i = 0; i < 4; ++i) {
            float4 v = *(const float4*)&hinit[hbase + 4 * i];
            h[4*i] = v.x; h[4*i+1] = v.y; h[4*i+2] = v.z; h[4*i+3] = v.w;
        }
        for (int st = 0; st < TCH; ++st) {
            const float* r = &sm[st * 40];
            float u = su[st * 192 + t];
            float xv = bias;
            #pragma unroll
            for (int j = 0; j < 6; ++j) xv += r[32 + j] * wdt[j];
            float delta = softplus_fast(xv);
            float du = delta * u;
            float acc = Dk * u;
            #pragma unroll
            for (int n = 0; n < 16; ++n) {
                float An = -__expf(Alog[kd * 16 + n]);
                h[n] = fmaf(h[n], __expf(delta * An), du * r[n]);
                acc  = fmaf(h[n], r[16 + n], acc);
            }
            *yp = acc;
            yp += ystep;
        }
    }
}

// ---------------------------------------------------------------------------
// K5: sum 4 direction buffers + LayerNorm + SiLU gate + out_proj.
__global__ __launch_bounds__(192) void k_lnout(const float* __restrict__ yk,
                                               const float* __restrict__ zb,
                                               const float* __restrict__ onw,
                                               const float* __restrict__ onb,
                                               const float* __restrict__ Wo,
                                               float* __restrict__ out)
{
    __shared__ float ys[1536];
    __shared__ float ps[192], pq[192];
    __shared__ float mu[8], ri[8];
    const int t   = threadIdx.x;
    const int p0  = blockIdx.x * 8;
    const int b   = p0 >> 12;
    const int pp0 = p0 & 4095;
    const size_t KSTR = (size_t)4096 * 192;

    #pragma unroll
    for (int i = 0; i < 8; ++i) {
        size_t base = ((size_t)(b * 4) * 4096 + pp0 + i) * 192 + t;
        ys[i * 192 + t] = yk[base] + yk[base + KSTR] + yk[base + 2 * KSTR] + yk[base + 3 * KSTR];
    }
    __syncthreads();

    {
        int pg = t / 24, j = t % 24;
        float s1 = 0.f, s2 = 0.f;
        #pragma unroll
        for (int m = 0; m < 8; ++m) {
            float v = ys[pg * 192 + j + 24 * m];
            s1 += v; s2 += v * v;
        }
        ps[t] = s1; pq[t] = s2;
    }
    __syncthreads();
    if (t < 8) {
        float s1 = 0.f, s2 = 0.f;
        #pragma unroll
        for (int j = 0; j < 24; ++j) { s1 += ps[t * 24 + j]; s2 += pq[t * 24 + j]; }
        float mean = s1 * (1.f / 192.f);
        float var  = s2 * (1.f / 192.f) - mean * mean;
        mu[t] = mean;
        ri[t] = rsqrtf(var + 1e-5f);
    }
    __syncthreads();

    {
        float w = onw[t], bo = onb[t];
        #pragma unroll
        for (int i = 0; i < 8; ++i) {
            float v  = ys[i * 192 + t];
            float yn = (v - mu[i]) * ri[i] * w + bo;
            float zv = zb[(size_t)(p0 + i) * 192 + t];
            float sg = 1.f / (1.f + __expf(-zv));
            ys[i * 192 + t] = yn * (zv * sg);
        }
    }
    __syncthreads();

    const int pg = t / 96, c = t % 96;
    float acc[4];
    #pragma unroll
    for (int i = 0; i < 4; ++i) acc[i] = 0.f;
    const float* wr = Wo + (size_t)c * 192;
    for (int k = 0; k < 192; k += 4) {
        float4 w = *(const float4*)(wr + k);
        #pragma unroll
        for (int i = 0; i < 4; ++i) {
            float4 xv = *(const float4*)&ys[(pg * 4 + i) * 192 + k];
            acc[i] = fmaf(w.x, xv.x, fmaf(w.y, xv.y, fmaf(w.z, xv.z, fmaf(w.w, xv.w, acc[i]))));
        }
    }
    #pragma unroll
    for (int i = 0; i < 4; ++i)
        out[(size_t)(p0 + pg * 4 + i) * 96 + c] = acc[i];
}

// ---------------------------------------------------------------------------
extern "C" void kernel_launch(void* const* d_in, const int* in_sizes, int n_in,
                              void* d_out, int out_size, void* d_ws, size_t ws_size,
                              hipStream_t stream)
{
    const float* x    = (const float*)d_in[0];
    const float* Wp   = (const float*)d_in[1];
    const float* cw   = (const float*)d_in[2];
    const float* cb   = (const float*)d_in[3];
    const float* xpw  = (const float*)d_in[4];
    const float* dtw  = (const float*)d_in[5];
    const float* dtb  = (const float*)d_in[6];
    const float* Alog = (const float*)d_in[7];
    const float* Ds   = (const float*)d_in[8];
    const float* onw  = (const float*)d_in[9];
    const float* onb  = (const float*)d_in[10];
    const float* Wo   = (const float*)d_in[11];
    float* out = (float*)d_out;

    const size_t NBP  = (size_t)BP_TOT * 192;        // 1.57M floats
    const size_t NXD  = (size_t)BB * 4 * 4096 * 38;  // 1.25M floats
    const size_t NSC  = (size_t)BB * 4 * SCH * 3072; // 3.15M floats
    const size_t NW   = (size_t)BB * 4 * SCH * 192;  // 0.20M floats
    float* WS    = (float*)d_ws;
    float* zb    = WS;                  // gate z
    float* xc    = WS + NBP;            // conv output (scan u)
    float* xdk   = WS + 2 * NBP;        // (b,k,l,38) scan-ordered x_dbl
    float* hend  = xdk + NXD;
    float* prodA = hend + NSC;          // general-path prodA; after scan2: h_init
    float* Wbuf  = prodA + NSC;         // fast-path scalar chunk decay
    float* yk    = Wbuf + NW;           // 4 per-direction y buffers (25 MB)

    k_fused <<<1024, 192, 0, stream>>>(x, Wp, cw, cb, xpw, zb, xc, xdk);
    k_scan1 <<<1024, 192, 0, stream>>>(xc, xdk, dtw, dtb, Alog, hend, prodA, Wbuf);
    k_scan2 <<<1536, 256, 0, stream>>>(hend, prodA, Wbuf, Alog);
    k_scan3 <<<1024, 192, 0, stream>>>(xc, xdk, dtw, dtb, Alog, Ds, prodA, yk);
    k_lnout <<<1024, 192, 0, stream>>>(yk, zb, onw, onb, Wo, out);
}

// Round 14
// 199.476 us; speedup vs baseline: 4.1609x; 1.1357x over previous
//
#include <hip/hip_runtime.h>
#include <math.h>

// Problem constants
#define DMODEL 96
#define DIN    192
#define NST    16
#define RK     6
#define KDIR   4
#define LLEN   4096   // H*W
#define BB     2
#define BP_TOT 8192   // B*L
#define SCH    128    // scan chunks per (b,k)
#define TCH    32     // steps per chunk (L/SCH)

typedef float v2f __attribute__((ext_vector_type(2)));

#if __has_builtin(__builtin_elementwise_fma)
__device__ __forceinline__ v2f pk_fma(v2f a, v2f b, v2f c) { return __builtin_elementwise_fma(a, b, c); }
#else
__device__ __forceinline__ v2f pk_fma(v2f a, v2f b, v2f c) { return a * b + c; }
#endif

// ---------------------------------------------------------------------------
// K1: in_proj. 1024 blocks x 192 thr, 8 positions/block.
__global__ __launch_bounds__(192) void k_inproj(const float* __restrict__ x,
                                                const float* __restrict__ Wp,
                                                float* __restrict__ xi,
                                                float* __restrict__ z)
{
    __shared__ float xs[8 * 96];
    const int t  = threadIdx.x;
    const int p0 = blockIdx.x * 8;
    for (int idx = t; idx < 768; idx += 192)
        xs[idx] = x[(size_t)p0 * 96 + idx];
    __syncthreads();

    float acc0[8], acc1[8];
    #pragma unroll
    for (int i = 0; i < 8; ++i) { acc0[i] = 0.f; acc1[i] = 0.f; }
    const float* w0p = Wp + (size_t)t * 96;
    const float* w1p = Wp + (size_t)(t + 192) * 96;
    for (int k = 0; k < 96; k += 4) {
        float4 w0 = *(const float4*)(w0p + k);
        float4 w1 = *(const float4*)(w1p + k);
        #pragma unroll
        for (int p = 0; p < 8; ++p) {
            float4 xv = *(const float4*)&xs[p * 96 + k];
            acc0[p] = fmaf(w0.x, xv.x, fmaf(w0.y, xv.y, fmaf(w0.z, xv.z, fmaf(w0.w, xv.w, acc0[p]))));
            acc1[p] = fmaf(w1.x, xv.x, fmaf(w1.y, xv.y, fmaf(w1.z, xv.z, fmaf(w1.w, xv.w, acc1[p]))));
        }
    }
    #pragma unroll
    for (int p = 0; p < 8; ++p) {
        xi[(size_t)(p0 + p) * 192 + t] = acc0[p];
        z [(size_t)(p0 + p) * 192 + t] = acc1[p];
    }
}

// ---------------------------------------------------------------------------
__device__ __forceinline__ int inv_perm(int kd, int p)
{
    if (kd == 0) return p;
    if (kd == 1) return ((p & 63) << 6) | (p >> 6);
    if (kd == 2) return 4095 - p;
    return 4095 - (((p & 63) << 6) | (p >> 6));
}

__device__ __forceinline__ int perm_pos(int k, int l)
{
    if (k == 0) return l;
    if (k == 1) return ((l & 63) << 6) | (l >> 6);
    if (k == 2) return 4095 - l;
    int lr = 4095 - l;
    return ((lr & 63) << 6) | (lr >> 6);
}

// within a 32-aligned chunk, perm_pos(k, l0+st) = perm_pos(k,l0) + st*dir
__device__ __forceinline__ int perm_dir(int k)
{
    return (k == 0) ? 1 : (k == 1) ? 64 : (k == 2) ? -1 : -64;
}

__device__ __forceinline__ float softplus_fast(float x)
{
    float r = __logf(1.f + __expf(x));
    return (x > 15.f) ? x : r;
}

// packed power chain: aa[i] = (e1^(2i+1), e1^(2i+2)), i in [0,8)
__device__ __forceinline__ void pow_chain_pk(float e1, v2f* aa)
{
    float e2 = e1 * e1;
    v2f a0; a0.x = e1; a0.y = e2;
    v2f s2; s2.x = e2; s2.y = e2;
    v2f a1 = a0 * s2;                  // e3,e4
    float e4 = a1.y;
    v2f s4; s4.x = e4; s4.y = e4;
    v2f a2 = a0 * s4;                  // e5,e6
    v2f a3 = a1 * s4;                  // e7,e8
    float e8 = a3.y;
    v2f s8; s8.x = e8; s8.y = e8;
    aa[0] = a0; aa[1] = a1; aa[2] = a2; aa[3] = a3;
    aa[4] = a0 * s8;                   // e9,e10
    aa[5] = a1 * s8;                   // e11,e12
    aa[6] = a2 * s8;                   // e13,e14
    aa[7] = a3 * s8;                   // e15,e16
}

// single power W^(n+1), e = n+1 in [1,16]
__device__ __forceinline__ float pow_n(float W, int e)
{
    float w2 = W * W, w4 = w2 * w2, w8 = w4 * w4;
    float r = 1.f;
    if (e & 1) r *= W;
    if (e & 2) r *= w2;
    if (e & 4) r *= w4;
    if (e & 8) r *= w8;
    if (e & 16) r = w8 * w8;
    return r;
}

// scan-kernel LDS layout per step (stride 40): B[0..15], C[16..31], dt[32..37]
__device__ __forceinline__ int sm_remap(int c)  // src col c: 0..5 dt, 6..21 B, 22..37 C
{
    return (c < 6) ? (32 + c) : (c - 6);
}

// ---------------------------------------------------------------------------
// K2: fused depthwise conv(3x3)+SiLU + x_proj GEMM (scan-ordered out).
__global__ __launch_bounds__(192) void k_convxdbl(const float* __restrict__ xi,
                                                  const float* __restrict__ cw,
                                                  const float* __restrict__ cb,
                                                  const float* __restrict__ xpw,
                                                  float* __restrict__ xc,
                                                  float* __restrict__ xdk)
{
    __shared__ float xs[8 * 192];
    const int t   = threadIdx.x;
    const int p0  = blockIdx.x * 8;
    const int b   = p0 >> 12;
    const int pp0 = p0 & 4095;
    const int row = pp0 >> 6, c0 = pp0 & 63;

    float w9[9];
    #pragma unroll
    for (int i = 0; i < 9; ++i) w9[i] = cw[t * 9 + i];
    const float cbias = cb[t];

    float xv[3][10];
    #pragma unroll
    for (int ky = 0; ky < 3; ++ky) {
        int rr = row + ky - 1;
        #pragma unroll
        for (int kx = 0; kx < 10; ++kx) {
            int cc = c0 + kx - 1;
            float v = 0.f;
            if (rr >= 0 && rr < 64 && cc >= 0 && cc < 64)
                v = xi[((size_t)b * 4096 + rr * 64 + cc) * 192 + t];
            xv[ky][kx] = v;
        }
    }
    #pragma unroll
    for (int p = 0; p < 8; ++p) {
        float s = cbias;
        #pragma unroll
        for (int ky = 0; ky < 3; ++ky)
            #pragma unroll
            for (int kx = 0; kx < 3; ++kx)
                s = fmaf(xv[ky][p + kx], w9[ky * 3 + kx], s);
        float sv = s * (1.f / (1.f + __expf(-s)));   // SiLU
        xc[(size_t)(p0 + p) * 192 + t] = sv;
        xs[p * 192 + t] = sv;
    }
    __syncthreads();
    if (t >= 152) return;

    const int kd = t / 38, r = t % 38;
    float acc[8];
    #pragma unroll
    for (int i = 0; i < 8; ++i) acc[i] = 0.f;
    const float* wr = xpw + (size_t)t * 192;
    for (int k = 0; k < 192; k += 4) {
        float4 w = *(const float4*)(wr + k);
        #pragma unroll
        for (int p = 0; p < 8; ++p) {
            float4 x4 = *(const float4*)&xs[p * 192 + k];
            acc[p] = fmaf(w.x, x4.x, fmaf(w.y, x4.y, fmaf(w.z, x4.z, fmaf(w.w, x4.w, acc[p]))));
        }
    }
    #pragma unroll
    for (int p = 0; p < 8; ++p) {
        int pp = pp0 + p;
        int l  = inv_perm(kd, pp);
        xdk[((size_t)(b * 4 + kd) * 4096 + l) * 38 + r] = acc[p];
    }
}

// ---------------------------------------------------------------------------
// K3: scan pass 1 — local recurrence from h=0. Pure LDS+VALU inner loop;
// fast path packed fp32 (v_pk_fma_f32). Stores h_end and W (fast) / prodA.
__global__ __launch_bounds__(192) void k_scan1(const float* __restrict__ xc,
                                               const float* __restrict__ xdk,
                                               const float* __restrict__ dtw,
                                               const float* __restrict__ dtb,
                                               const float* __restrict__ Alog,
                                               float* __restrict__ hend,
                                               float* __restrict__ prodA,
                                               float* __restrict__ Wbuf)
{
    __shared__ float sm[TCH * 40];
    __shared__ float su[TCH * 192];
    const int t   = threadIdx.x;
    const int blk = blockIdx.x;
    const int s = blk & (SCH - 1), k = (blk >> 7) & 3, b = blk >> 9;
    const int kd = k * 192 + t;
    const int l0 = s * TCH;
    const int pstart = perm_pos(k, l0);
    const int dir    = perm_dir(k);

    const float* src = xdk + ((size_t)(b * 4 + k) * 4096 + l0) * 38;
    for (int idx = t; idx < TCH * 38; idx += 192) {
        int st = idx / 38, c = idx % 38;
        sm[st * 40 + sm_remap(c)] = src[idx];
    }
    const float* xcb = xc + (size_t)b * 4096 * 192;
    #pragma unroll
    for (int i = 0; i < TCH; ++i)
        su[i * 192 + t] = xcb[(size_t)(pstart + i * dir) * 192 + t];

    const float A0 = -__expf(Alog[kd * 16]);
    bool fast = true;
    #pragma unroll
    for (int n = 1; n < 16; ++n) {
        float An = -__expf(Alog[kd * 16 + n]);
        fast = fast && (fabsf(An - (float)(n + 1) * A0) <= 1e-3f * fabsf(An));
    }
    float wdt[6];
    #pragma unroll
    for (int r = 0; r < 6; ++r) wdt[r] = dtw[kd * 6 + r];
    const float bias = dtb[kd];

    __syncthreads();

    size_t base = (size_t)blk * 3072 + t * 16;

    if (fast) {
        v2f h2[8];
        #pragma unroll
        for (int i = 0; i < 8; ++i) { h2[i].x = 0.f; h2[i].y = 0.f; }
        float cd = 0.f;
        for (int st = 0; st < TCH; ++st) {
            const float* r = &sm[st * 40];
            float u = su[st * 192 + t];
            float4 dq = *(const float4*)(r + 32);
            float xv = bias + dq.x * wdt[0] + dq.y * wdt[1] + dq.z * wdt[2]
                            + dq.w * wdt[3] + r[36] * wdt[4] + r[37] * wdt[5];
            float delta = softplus_fast(xv);
            cd += delta;
            float du = delta * u;
            v2f du2; du2.x = du; du2.y = du;
            v2f aa2[8];
            pow_chain_pk(__expf(delta * A0), aa2);
            const v2f* rb = (const v2f*)r;
            #pragma unroll
            for (int i = 0; i < 8; ++i)
                h2[i] = pk_fma(h2[i], aa2[i], du2 * rb[i]);
        }
        Wbuf[(size_t)blk * 192 + t] = __expf(cd * A0);
        #pragma unroll
        for (int i = 0; i < 4; ++i)
            *(float4*)&hend[base + 4 * i] =
                make_float4(h2[2*i].x, h2[2*i].y, h2[2*i+1].x, h2[2*i+1].y);
    } else {
        float h[16];
        #pragma unroll
        for (int n = 0; n < 16; ++n) h[n] = 0.f;
        float cd = 0.f;
        for (int st = 0; st < TCH; ++st) {
            const float* r = &sm[st * 40];
            float u = su[st * 192 + t];
            float xv = bias;
            #pragma unroll
            for (int j = 0; j < 6; ++j) xv += r[32 + j] * wdt[j];
            float delta = softplus_fast(xv);
            cd += delta;
            float du = delta * u;
            #pragma unroll
            for (int n = 0; n < 16; ++n) {
                float An = -__expf(Alog[kd * 16 + n]);
                h[n] = fmaf(h[n], __expf(delta * An), du * r[n]);
            }
        }
        #pragma unroll
        for (int n = 0; n < 16; ++n)
            prodA[base + n] = __expf(-__expf(Alog[kd * 16 + n]) * cd);
        #pragma unroll
        for (int i = 0; i < 4; ++i)
            *(float4*)&hend[base + 4 * i] = make_float4(h[4*i], h[4*i+1], h[4*i+2], h[4*i+3]);
    }
}

// ---------------------------------------------------------------------------
// K4: scan pass 2 — parallel chunk composition. Block=(b,k,d). Fast path
// reconstructs a[n] = W^(n+1) from the scalar Wbuf. Writes h_init into prodA.
__global__ __launch_bounds__(256) void k_scan2(const float* __restrict__ hend,
                                               float* __restrict__ prodA,
                                               const float* __restrict__ Wbuf,
                                               const float* __restrict__ Alog)
{
    __shared__ float smA[256], smH[256];
    const int t = threadIdx.x;
    const int g = t >> 4, n = t & 15;
    const int bk = blockIdx.x / 192, d = blockIdx.x % 192;
    const int kd = (bk & 3) * 192 + d;
    const size_t base = (size_t)bk * SCH * 3072 + d * 16 + n;

    const float A0 = -__expf(Alog[kd * 16]);
    bool fast = true;
    #pragma unroll
    for (int m = 1; m < 16; ++m) {
        float An = -__expf(Alog[kd * 16 + m]);
        fast = fast && (fabsf(An - (float)(m + 1) * A0) <= 1e-3f * fabsf(An));
    }

    float a_[8], h_[8];
    float A = 1.f, H = 0.f;
    #pragma unroll
    for (int i = 0; i < 8; ++i) {
        int s = g * 8 + i;
        size_t rec = base + (size_t)s * 3072;
        float ai;
        if (fast) {
            float W = Wbuf[((size_t)bk * SCH + s) * 192 + d];
            ai = pow_n(W, n + 1);
        } else {
            ai = prodA[rec];
        }
        a_[i] = ai;
        h_[i] = hend[rec];
        H = fmaf(ai, H, h_[i]);
        A *= ai;
    }
    smA[t] = A; smH[t] = H;
    __syncthreads();
    if (t < 16) {
        float carry = 0.f;
        for (int g2 = 0; g2 < 16; ++g2) {
            float ta = smA[g2 * 16 + t], th = smH[g2 * 16 + t];
            smH[g2 * 16 + t] = carry;          // exclusive carry into group g2
            carry = fmaf(ta, carry, th);
        }
    }
    __syncthreads();
    float carry = smH[t];
    #pragma unroll
    for (int i = 0; i < 8; ++i) {
        size_t rec = base + (size_t)(g * 8 + i) * 3072;
        prodA[rec] = carry;                    // h_init
        carry = fmaf(a_[i], carry, h_[i]);
    }
}

// ---------------------------------------------------------------------------
// K5: scan pass 3 — full replay from h_init, write yk once (plain stores).
// Packed fp32 fast path; incremental y pointer.
__global__ __launch_bounds__(192) void k_scan3(const float* __restrict__ xc,
                                               const float* __restrict__ xdk,
                                               const float* __restrict__ dtw,
                                               const float* __restrict__ dtb,
                                               const float* __restrict__ Alog,
                                               const float* __restrict__ Ds,
                                               const float* __restrict__ hinit,
                                               float* __restrict__ yk)
{
    __shared__ float sm[TCH * 40];
    __shared__ float su[TCH * 192];
    const int t   = threadIdx.x;
    const int blk = blockIdx.x;
    const int s = blk & (SCH - 1), k = (blk >> 7) & 3, b = blk >> 9;
    const int kd = k * 192 + t;
    const int l0 = s * TCH;
    const int pstart = perm_pos(k, l0);
    const int dir    = perm_dir(k);

    const float* src = xdk + ((size_t)(b * 4 + k) * 4096 + l0) * 38;
    for (int idx = t; idx < TCH * 38; idx += 192) {
        int st = idx / 38, c = idx % 38;
        sm[st * 40 + sm_remap(c)] = src[idx];
    }
    const float* xcb = xc + (size_t)b * 4096 * 192;
    #pragma unroll
    for (int i = 0; i < TCH; ++i)
        su[i * 192 + t] = xcb[(size_t)(pstart + i * dir) * 192 + t];

    const float A0 = -__expf(Alog[kd * 16]);
    bool fast = true;
    #pragma unroll
    for (int n = 1; n < 16; ++n) {
        float An = -__expf(Alog[kd * 16 + n]);
        fast = fast && (fabsf(An - (float)(n + 1) * A0) <= 1e-3f * fabsf(An));
    }
    float wdt[6];
    #pragma unroll
    for (int r = 0; r < 6; ++r) wdt[r] = dtw[kd * 6 + r];
    const float bias = dtb[kd];
    const float Dk   = Ds[kd];

    size_t hbase = (size_t)blk * 3072 + t * 16;
    float* yp = yk + (size_t)(b * 4 + k) * 4096 * 192 + (size_t)pstart * 192 + t;
    const int ystep = dir * 192;

    __syncthreads();

    if (fast) {
        v2f h2[8];
        #pragma unroll
        for (int i = 0; i < 4; ++i) {
            float4 v = *(const float4*)&hinit[hbase + 4 * i];
            h2[2*i].x = v.x; h2[2*i].y = v.y; h2[2*i+1].x = v.z; h2[2*i+1].y = v.w;
        }
        for (int st = 0; st < TCH; ++st) {
            const float* r = &sm[st * 40];
            float u = su[st * 192 + t];
            float4 dq = *(const float4*)(r + 32);
            float xv = bias + dq.x * wdt[0] + dq.y * wdt[1] + dq.z * wdt[2]
                            + dq.w * wdt[3] + r[36] * wdt[4] + r[37] * wdt[5];
            float delta = softplus_fast(xv);
            float du = delta * u;
            v2f du2; du2.x = du; du2.y = du;
            v2f aa2[8];
            pow_chain_pk(__expf(delta * A0), aa2);
            const v2f* rb = (const v2f*)r;
            const v2f* rc = (const v2f*)(r + 16);
            v2f acc2; acc2.x = Dk * u; acc2.y = 0.f;
            #pragma unroll
            for (int i = 0; i < 8; ++i) {
                h2[i] = pk_fma(h2[i], aa2[i], du2 * rb[i]);
                acc2  = pk_fma(h2[i], rc[i], acc2);
            }
            *yp = acc2.x + acc2.y;             // plain store, owner-exclusive
            yp += ystep;
        }
    } else {
        float h[16];
        #pragma unroll
        for (int i = 0; i < 4; ++i) {
            float4 v = *(const float4*)&hinit[hbase + 4 * i];
            h[4*i] = v.x; h[4*i+1] = v.y; h[4*i+2] = v.z; h[4*i+3] = v.w;
        }
        for (int st = 0; st < TCH; ++st) {
            const float* r = &sm[st * 40];
            float u = su[st * 192 + t];
            float xv = bias;
            #pragma unroll
            for (int j = 0; j < 6; ++j) xv += r[32 + j] * wdt[j];
            float delta = softplus_fast(xv);
            float du = delta * u;
            float acc = Dk * u;
            #pragma unroll
            for (int n = 0; n < 16; ++n) {
                float An = -__expf(Alog[kd * 16 + n]);
                h[n] = fmaf(h[n], __expf(delta * An), du * r[n]);
                acc  = fmaf(h[n], r[16 + n], acc);
            }
            *yp = acc;
            yp += ystep;
        }
    }
}

// ---------------------------------------------------------------------------
// K6: sum 4 direction buffers + LayerNorm + SiLU gate + out_proj.
__global__ __launch_bounds__(192) void k_lnout(const float* __restrict__ yk,
                                               const float* __restrict__ zb,
                                               const float* __restrict__ onw,
                                               const float* __restrict__ onb,
                                               const float* __restrict__ Wo,
                                               float* __restrict__ out)
{
    __shared__ float ys[1536];
    __shared__ float ps[192], pq[192];
    __shared__ float mu[8], ri[8];
    const int t   = threadIdx.x;
    const int p0  = blockIdx.x * 8;
    const int b   = p0 >> 12;
    const int pp0 = p0 & 4095;
    const size_t KSTR = (size_t)4096 * 192;

    #pragma unroll
    for (int i = 0; i < 8; ++i) {
        size_t base = ((size_t)(b * 4) * 4096 + pp0 + i) * 192 + t;
        ys[i * 192 + t] = yk[base] + yk[base + KSTR] + yk[base + 2 * KSTR] + yk[base + 3 * KSTR];
    }
    __syncthreads();

    {
        int pg = t / 24, j = t % 24;
        float s1 = 0.f, s2 = 0.f;
        #pragma unroll
        for (int m = 0; m < 8; ++m) {
            float v = ys[pg * 192 + j + 24 * m];
            s1 += v; s2 += v * v;
        }
        ps[t] = s1; pq[t] = s2;
    }
    __syncthreads();
    if (t < 8) {
        float s1 = 0.f, s2 = 0.f;
        #pragma unroll
        for (int j = 0; j < 24; ++j) { s1 += ps[t * 24 + j]; s2 += pq[t * 24 + j]; }
        float mean = s1 * (1.f / 192.f);
        float var  = s2 * (1.f / 192.f) - mean * mean;
        mu[t] = mean;
        ri[t] = rsqrtf(var + 1e-5f);
    }
    __syncthreads();

    {
        float w = onw[t], bo = onb[t];
        #pragma unroll
        for (int i = 0; i < 8; ++i) {
            float v  = ys[i * 192 + t];
            float yn = (v - mu[i]) * ri[i] * w + bo;
            float zv = zb[(size_t)(p0 + i) * 192 + t];
            float sg = 1.f / (1.f + __expf(-zv));
            ys[i * 192 + t] = yn * (zv * sg);
        }
    }
    __syncthreads();

    const int pg = t / 96, c = t % 96;
    float acc[4];
    #pragma unroll
    for (int i = 0; i < 4; ++i) acc[i] = 0.f;
    const float* wr = Wo + (size_t)c * 192;
    for (int k = 0; k < 192; k += 4) {
        float4 w = *(const float4*)(wr + k);
        #pragma unroll
        for (int i = 0; i < 4; ++i) {
            float4 xv = *(const float4*)&ys[(pg * 4 + i) * 192 + k];
            acc[i] = fmaf(w.x, xv.x, fmaf(w.y, xv.y, fmaf(w.z, xv.z, fmaf(w.w, xv.w, acc[i]))));
        }
    }
    #pragma unroll
    for (int i = 0; i < 4; ++i)
        out[(size_t)(p0 + pg * 4 + i) * 96 + c] = acc[i];
}

// ---------------------------------------------------------------------------
extern "C" void kernel_launch(void* const* d_in, const int* in_sizes, int n_in,
                              void* d_out, int out_size, void* d_ws, size_t ws_size,
                              hipStream_t stream)
{
    const float* x    = (const float*)d_in[0];
    const float* Wp   = (const float*)d_in[1];
    const float* cw   = (const float*)d_in[2];
    const float* cb   = (const float*)d_in[3];
    const float* xpw  = (const float*)d_in[4];
    const float* dtw  = (const float*)d_in[5];
    const float* dtb  = (const float*)d_in[6];
    const float* Alog = (const float*)d_in[7];
    const float* Ds   = (const float*)d_in[8];
    const float* onw  = (const float*)d_in[9];
    const float* onb  = (const float*)d_in[10];
    const float* Wo   = (const float*)d_in[11];
    float* out = (float*)d_out;

    const size_t NBP  = (size_t)BP_TOT * 192;        // 1.57M floats
    const size_t NXD  = (size_t)BB * 4 * 4096 * 38;  // 1.25M floats
    const size_t NSC  = (size_t)BB * 4 * SCH * 3072; // 3.15M floats
    const size_t NW   = (size_t)BB * 4 * SCH * 192;  // 0.20M floats
    float* WS    = (float*)d_ws;
    float* xibuf = WS;                  // in_proj x-branch (conv input)
    float* zb    = WS + NBP;            // gate z
    float* xc    = WS + 2 * NBP;        // conv output (scan u)
    float* xdk   = WS + 3 * NBP;        // (b,k,l,38) scan-ordered x_dbl
    float* hend  = xdk + NXD;
    float* prodA = hend + NSC;          // general-path prodA; after scan2: h_init
    float* Wbuf  = prodA + NSC;         // fast-path scalar chunk decay
    float* yk    = Wbuf + NW;           // 4 per-direction y buffers (25 MB)

    k_inproj  <<<1024, 192, 0, stream>>>(x, Wp, xibuf, zb);
    k_convxdbl<<<1024, 192, 0, stream>>>(xibuf, cw, cb, xpw, xc, xdk);
    k_scan1   <<<1024, 192, 0, stream>>>(xc, xdk, dtw, dtb, Alog, hend, prodA, Wbuf);
    k_scan2   <<<1536, 256, 0, stream>>>(hend, prodA, Wbuf, Alog);
    k_scan3   <<<1024, 192, 0, stream>>>(xc, xdk, dtw, dtb, Alog, Ds, prodA, yk);
    k_lnout   <<<1024, 192, 0, stream>>>(yk, zb, onw, onb, Wo, out);
}